// Round 1
// baseline (135.452 us; speedup 1.0000x reference)
//
#include <hip/hip_runtime.h>
#include <math.h>

// EnhancedFinancialGAT — analytical collapse (Round 0 proof: all N=2000 node
// rows identical + per-dst softmax sums to 1 (self-loop guarantees denom>=1)
// => each GAT layer is a dense 256->256 relu; edges/attention irrelevant).
//
// Round 7: single-kernel. R6 established cross-layer register prefetch; the
// remaining structural overhead was the compress_w prepass (extra launch +
// full dependency + 1.5 MB d_ws write/read round-trip re-done every iteration
// because the workspace is re-poisoned). R5 showed weight BYTES are neutral,
// so fp16 compression buys nothing at load time: read fp32 weights directly
// and convert to fp16 in-register with the same RTN casts (identical
// numerics, identical frag register footprint). d_ws is now unused.

#define B_ITEMS 64

typedef _Float16 half_t;
typedef _Float16 half8 __attribute__((ext_vector_type(8)));

// ---- bias layout in LDS (float offsets) ----
#define BIN   0      // 256
#define BGAT  256    // 768 (3*256)
#define BFUSE 1024   // 256
#define BP1   1280   // 128
#define BD1   1408   // 128
#define BP2   1536   // 64
#define BD2   1600   // 64
#define NBIAS 1664

// Weight fragment for one layer: this lane's K-slice of its output row.
template <int K, int G>
struct WFrag { half8 w[K / (8 * G)]; };

// Load this lane's K-slice of output row o directly from the fp32 weight
// matrix [M][K], converting to fp16 in-register (RTN casts — bit-identical
// to the old compress_w prepass, so numerics are unchanged).
template <int K, int G>
__device__ __forceinline__ void load_frag(WFrag<K, G>& f,
                                          const float* __restrict__ W, int t) {
    const int c = t & (G - 1);
    const int o = t / G;
    const float4* __restrict__ W4 =
        reinterpret_cast<const float4*>(W + (size_t)o * K);
#pragma unroll
    for (int j = 0; j < K / (8 * G); ++j) {
        const int idx = j * G + c;
        float4 a = W4[2 * idx];
        float4 b = W4[2 * idx + 1];
        f.w[j] = half8{ (_Float16)a.x, (_Float16)a.y, (_Float16)a.z, (_Float16)a.w,
                        (_Float16)b.x, (_Float16)b.y, (_Float16)b.z, (_Float16)b.w };
    }
}

// out[M] = relu(frag @ in + b), frag already in registers. t in [0, M*G).
template <int M, int K, int G>
__device__ __forceinline__ void compute_frag(const WFrag<K, G>& f,
                                             const float* __restrict__ bias,  // LDS
                                             const float* __restrict__ in,    // LDS
                                             float* __restrict__ out,         // LDS
                                             int t) {
    const int c = t & (G - 1);
    const int o = t / G;
    const float4* __restrict__ A4 = reinterpret_cast<const float4*>(in);
    float acc = 0.f;
#pragma unroll
    for (int j = 0; j < K / (8 * G); ++j) {
        const int idx = j * G + c;
        float4 a0 = A4[2 * idx];
        float4 a1 = A4[2 * idx + 1];
        half8 w = f.w[j];
        acc = fmaf((float)w[0], a0.x, acc);
        acc = fmaf((float)w[1], a0.y, acc);
        acc = fmaf((float)w[2], a0.z, acc);
        acc = fmaf((float)w[3], a0.w, acc);
        acc = fmaf((float)w[4], a1.x, acc);
        acc = fmaf((float)w[5], a1.y, acc);
        acc = fmaf((float)w[6], a1.z, acc);
        acc = fmaf((float)w[7], a1.w, acc);
    }
#pragma unroll
    for (int s = 1; s < G; s <<= 1) acc += __shfl_xor(acc, s, 64);
    if (c == 0) out[o] = fmaxf(acc + bias[o], 0.f);
}

extern "C" __global__ __launch_bounds__(1024) void fin_gat_v7(
    const float* __restrict__ x,        // [64,64]
    const int* __restrict__ cidx,       // [64]
    const float* __restrict__ W_in,     // [256,64]
    const float* __restrict__ b_in,
    const float* __restrict__ gat_W,    // [3,256,256]
    const float* __restrict__ gat_b,    // [3,256]
    const float* __restrict__ emb,      // [2000,64]
    const float* __restrict__ W_fuse,   // [256,320]
    const float* __restrict__ b_fuse,
    const float* __restrict__ W_p1,     // [128,256]
    const float* __restrict__ b_p1,
    const float* __restrict__ W_p2,     // [64,128]
    const float* __restrict__ b_p2,
    const float* __restrict__ W_p3, const float* __restrict__ b_p3,
    const float* __restrict__ W_d1,     // [128,256]
    const float* __restrict__ b_d1,
    const float* __restrict__ W_d2,     // [64,128]
    const float* __restrict__ b_d2,
    const float* __restrict__ W_d3, const float* __restrict__ b_d3,
    float* __restrict__ out)            // [128]
{
    __shared__ float bufA[320];
    __shared__ float bufB[320];
    __shared__ float bias_lds[NBIAS];

    const int b = blockIdx.x;
    const int t = threadIdx.x;

    // ---- initial burst: L0 weights, x/emb, all biases, head dot weights ----
    WFrag<64, 4> f_in;
    load_frag(f_in, W_in, t);

    if (t < 64) {
        const int ci = cidx[b];
        bufA[t] = x[b * 64 + t];
        bufA[256 + t] = emb[(size_t)ci * 64 + t];   // kept for fuse layer
    }
    float wdot = 0.f, bdot = 0.f;
    if (t < 64)            wdot = W_p3[t];
    else if (t < 128)      wdot = W_d3[t - 64];
    if (t == 0)            bdot = b_p3[0];
    else if (t == 64)      bdot = b_d3[0];

#pragma unroll
    for (int i = t; i < NBIAS; i += 1024) {
        float v;
        if      (i < 256)  v = b_in[i];
        else if (i < 1024) v = gat_b[i - 256];
        else if (i < 1280) v = b_fuse[i - 1024];
        else if (i < 1408) v = b_p1[i - 1280];
        else if (i < 1536) v = b_d1[i - 1408];
        else if (i < 1600) v = b_p2[i - 1536];
        else               v = b_d2[i - 1600];
        bias_lds[i] = v;
    }
    __syncthreads();

    // ---- L0: h = relu(W_in x): A[0:64] -> B[0:256] ----
    WFrag<256, 4> fg0;
    load_frag(fg0, gat_W + 0 * 65536, t);                   // prefetch L1
    compute_frag<256, 64, 4>(f_in, bias_lds + BIN, bufA, bufB, t);
    __syncthreads();

    // ---- L1 (GAT1): B -> A[0:256]  (emb intact in A[256:320]) ----
    WFrag<256, 4> fg1;
    load_frag(fg1, gat_W + 1 * 65536, t);                   // prefetch L2
    compute_frag<256, 256, 4>(fg0, bias_lds + BGAT, bufB, bufA, t);
    __syncthreads();

    // ---- L2 (GAT2): A -> B ----
    WFrag<256, 4> fg2;
    load_frag(fg2, gat_W + 2 * 65536, t);                   // prefetch L3
    compute_frag<256, 256, 4>(fg1, bias_lds + BGAT + 256, bufA, bufB, t);
    __syncthreads();

    // ---- L3 (GAT3): B -> A[0:256] ----
    WFrag<320, 4> f_fu;
    load_frag(f_fu, W_fuse, t);                             // prefetch fuse
    compute_frag<256, 256, 4>(fg2, bias_lds + BGAT + 512, bufB, bufA, t);
    __syncthreads();

    // ---- L4 (fuse): A[0:320] -> B[0:256] ----
    WFrag<256, 4> f_h1;
    load_frag(f_h1, (t < 512) ? W_p1 : W_d1, t & 511);      // prefetch heads-1
    compute_frag<256, 320, 4>(f_fu, bias_lds + BFUSE, bufA, bufB, t);
    __syncthreads();

    // ---- L5: p1 (lower half-block) / d1 (upper half-block) ----
    WFrag<128, 8> f_h2;
    load_frag(f_h2, (t < 512) ? W_p2 : W_d2, t & 511);      // prefetch heads-2
    if (t < 512) compute_frag<128, 256, 4>(f_h1, bias_lds + BP1, bufB, bufA, t);
    else         compute_frag<128, 256, 4>(f_h1, bias_lds + BD1, bufB, bufA + 192, t - 512);
    __syncthreads();

    // ---- L6: p2 / d2 ----
    if (t < 512) compute_frag<64, 128, 8>(f_h2, bias_lds + BP2, bufA, bufB, t);
    else         compute_frag<64, 128, 8>(f_h2, bias_lds + BD2, bufA + 192, bufB + 64, t - 512);
    __syncthreads();

    // ---- final dots (weights preloaded): wave 0 -> price, wave 1 -> dir ----
    if (t < 64) {
        float v = wdot * bufB[t];
#pragma unroll
        for (int off = 32; off > 0; off >>= 1) v += __shfl_down(v, off, 64);
        if (t == 0) out[b] = v + bdot;
    } else if (t < 128) {
        const int u = t - 64;
        float v = wdot * bufB[64 + u];
#pragma unroll
        for (int off = 32; off > 0; off >>= 1) v += __shfl_down(v, off, 64);
        if (u == 0) {
            float z = v + bdot;
            out[B_ITEMS + b] = 1.0f / (1.0f + expf(-z));
        }
    }
}

extern "C" void kernel_launch(void* const* d_in, const int* in_sizes, int n_in,
                              void* d_out, int out_size, void* d_ws, size_t ws_size,
                              hipStream_t stream) {
    const float* x      = (const float*)d_in[0];
    const int*   cidx   = (const int*)  d_in[1];
    // d_in[2]=edge_index, d_in[3]=edge_attr -> numerically irrelevant
    const float* W_in   = (const float*)d_in[4];
    const float* b_in   = (const float*)d_in[5];
    const float* gat_W  = (const float*)d_in[6];
    // d_in[7..10] = att params -> irrelevant
    const float* gat_b  = (const float*)d_in[11];
    const float* emb    = (const float*)d_in[12];
    const float* W_fuse = (const float*)d_in[13];
    const float* b_fuse = (const float*)d_in[14];
    const float* W_p1   = (const float*)d_in[15];
    const float* b_p1   = (const float*)d_in[16];
    const float* W_p2   = (const float*)d_in[17];
    const float* b_p2   = (const float*)d_in[18];
    const float* W_p3   = (const float*)d_in[19];
    const float* b_p3   = (const float*)d_in[20];
    const float* W_d1   = (const float*)d_in[21];
    const float* b_d1   = (const float*)d_in[22];
    const float* W_d2   = (const float*)d_in[23];
    const float* b_d2   = (const float*)d_in[24];
    const float* W_d3   = (const float*)d_in[25];
    const float* b_d3   = (const float*)d_in[26];

    // d_ws unused: the fp16 compression is now done in-register at load time
    // (workspace is re-poisoned every iteration, so a prepass could never be
    // hoisted anyway).
    (void)d_ws; (void)ws_size;

    fin_gat_v7<<<B_ITEMS, 1024, 0, stream>>>(
        x, cidx, W_in, b_in, gat_W, gat_b, emb, W_fuse, b_fuse,
        W_p1, b_p1, W_p2, b_p2, W_p3, b_p3,
        W_d1, b_d1, W_d2, b_d2, W_d3, b_d3,
        (float*)d_out);
}

// Round 2
// 134.664 us; speedup vs baseline: 1.0059x; 1.0059x over previous
//
#include <hip/hip_runtime.h>
#include <math.h>

// EnhancedFinancialGAT — analytical collapse (Round 0 proof: all N=2000 node
// rows identical + per-dst softmax sums to 1 (self-loop guarantees denom>=1)
// => each GAT layer is a dense 256->256 relu; edges/attention irrelevant).
//
// Round 8: fix R7's scratch-spill regression. R7 moved the fp32->fp16 weight
// compression in-register (single kernel, no d_ws round-trip) but the fp32
// load temporaries doubled register pressure; hipcc's occupancy heuristic
// pinned the kernel at 64 VGPRs and spilled ~34 VGPRs/thread to scratch
// (WRITE_SIZE 8.7 MB on a kernel that stores 512 B). Occupancy >1 block/CU
// is worthless here (64 blocks on 256 CUs), so grant the full 128-VGPR
// budget: __launch_bounds__(1024, 4) = 4 waves/EU = 1 block/CU.

#define B_ITEMS 64

typedef _Float16 half_t;
typedef _Float16 half8 __attribute__((ext_vector_type(8)));

// ---- bias layout in LDS (float offsets) ----
#define BIN   0      // 256
#define BGAT  256    // 768 (3*256)
#define BFUSE 1024   // 256
#define BP1   1280   // 128
#define BD1   1408   // 128
#define BP2   1536   // 64
#define BD2   1600   // 64
#define NBIAS 1664

// Weight fragment for one layer: this lane's K-slice of its output row.
template <int K, int G>
struct WFrag { half8 w[K / (8 * G)]; };

// Load this lane's K-slice of output row o directly from the fp32 weight
// matrix [M][K], converting to fp16 in-register (RTN casts — bit-identical
// to the old compress_w prepass, so numerics are unchanged).
template <int K, int G>
__device__ __forceinline__ void load_frag(WFrag<K, G>& f,
                                          const float* __restrict__ W, int t) {
    const int c = t & (G - 1);
    const int o = t / G;
    const float4* __restrict__ W4 =
        reinterpret_cast<const float4*>(W + (size_t)o * K);
#pragma unroll
    for (int j = 0; j < K / (8 * G); ++j) {
        const int idx = j * G + c;
        float4 a = W4[2 * idx];
        float4 b = W4[2 * idx + 1];
        f.w[j] = half8{ (_Float16)a.x, (_Float16)a.y, (_Float16)a.z, (_Float16)a.w,
                        (_Float16)b.x, (_Float16)b.y, (_Float16)b.z, (_Float16)b.w };
    }
}

// out[M] = relu(frag @ in + b), frag already in registers. t in [0, M*G).
template <int M, int K, int G>
__device__ __forceinline__ void compute_frag(const WFrag<K, G>& f,
                                             const float* __restrict__ bias,  // LDS
                                             const float* __restrict__ in,    // LDS
                                             float* __restrict__ out,         // LDS
                                             int t) {
    const int c = t & (G - 1);
    const int o = t / G;
    const float4* __restrict__ A4 = reinterpret_cast<const float4*>(in);
    float acc = 0.f;
#pragma unroll
    for (int j = 0; j < K / (8 * G); ++j) {
        const int idx = j * G + c;
        float4 a0 = A4[2 * idx];
        float4 a1 = A4[2 * idx + 1];
        half8 w = f.w[j];
        acc = fmaf((float)w[0], a0.x, acc);
        acc = fmaf((float)w[1], a0.y, acc);
        acc = fmaf((float)w[2], a0.z, acc);
        acc = fmaf((float)w[3], a0.w, acc);
        acc = fmaf((float)w[4], a1.x, acc);
        acc = fmaf((float)w[5], a1.y, acc);
        acc = fmaf((float)w[6], a1.z, acc);
        acc = fmaf((float)w[7], a1.w, acc);
    }
#pragma unroll
    for (int s = 1; s < G; s <<= 1) acc += __shfl_xor(acc, s, 64);
    if (c == 0) out[o] = fmaxf(acc + bias[o], 0.f);
}

extern "C" __global__ __launch_bounds__(1024, 4) void fin_gat_v8(
    const float* __restrict__ x,        // [64,64]
    const int* __restrict__ cidx,       // [64]
    const float* __restrict__ W_in,     // [256,64]
    const float* __restrict__ b_in,
    const float* __restrict__ gat_W,    // [3,256,256]
    const float* __restrict__ gat_b,    // [3,256]
    const float* __restrict__ emb,      // [2000,64]
    const float* __restrict__ W_fuse,   // [256,320]
    const float* __restrict__ b_fuse,
    const float* __restrict__ W_p1,     // [128,256]
    const float* __restrict__ b_p1,
    const float* __restrict__ W_p2,     // [64,128]
    const float* __restrict__ b_p2,
    const float* __restrict__ W_p3, const float* __restrict__ b_p3,
    const float* __restrict__ W_d1,     // [128,256]
    const float* __restrict__ b_d1,
    const float* __restrict__ W_d2,     // [64,128]
    const float* __restrict__ b_d2,
    const float* __restrict__ W_d3, const float* __restrict__ b_d3,
    float* __restrict__ out)            // [128]
{
    __shared__ float bufA[320];
    __shared__ float bufB[320];
    __shared__ float bias_lds[NBIAS];

    const int b = blockIdx.x;
    const int t = threadIdx.x;

    // ---- initial burst: L0 weights, x/emb, all biases, head dot weights ----
    WFrag<64, 4> f_in;
    load_frag(f_in, W_in, t);

    if (t < 64) {
        const int ci = cidx[b];
        bufA[t] = x[b * 64 + t];
        bufA[256 + t] = emb[(size_t)ci * 64 + t];   // kept for fuse layer
    }
    float wdot = 0.f, bdot = 0.f;
    if (t < 64)            wdot = W_p3[t];
    else if (t < 128)      wdot = W_d3[t - 64];
    if (t == 0)            bdot = b_p3[0];
    else if (t == 64)      bdot = b_d3[0];

#pragma unroll
    for (int i = t; i < NBIAS; i += 1024) {
        float v;
        if      (i < 256)  v = b_in[i];
        else if (i < 1024) v = gat_b[i - 256];
        else if (i < 1280) v = b_fuse[i - 1024];
        else if (i < 1408) v = b_p1[i - 1280];
        else if (i < 1536) v = b_d1[i - 1408];
        else if (i < 1600) v = b_p2[i - 1536];
        else               v = b_d2[i - 1600];
        bias_lds[i] = v;
    }
    __syncthreads();

    // ---- L0: h = relu(W_in x): A[0:64] -> B[0:256] ----
    WFrag<256, 4> fg0;
    load_frag(fg0, gat_W + 0 * 65536, t);                   // prefetch L1
    compute_frag<256, 64, 4>(f_in, bias_lds + BIN, bufA, bufB, t);
    __syncthreads();

    // ---- L1 (GAT1): B -> A[0:256]  (emb intact in A[256:320]) ----
    WFrag<256, 4> fg1;
    load_frag(fg1, gat_W + 1 * 65536, t);                   // prefetch L2
    compute_frag<256, 256, 4>(fg0, bias_lds + BGAT, bufB, bufA, t);
    __syncthreads();

    // ---- L2 (GAT2): A -> B ----
    WFrag<256, 4> fg2;
    load_frag(fg2, gat_W + 2 * 65536, t);                   // prefetch L3
    compute_frag<256, 256, 4>(fg1, bias_lds + BGAT + 256, bufA, bufB, t);
    __syncthreads();

    // ---- L3 (GAT3): B -> A[0:256] ----
    WFrag<320, 4> f_fu;
    load_frag(f_fu, W_fuse, t);                             // prefetch fuse
    compute_frag<256, 256, 4>(fg2, bias_lds + BGAT + 512, bufB, bufA, t);
    __syncthreads();

    // ---- L4 (fuse): A[0:320] -> B[0:256] ----
    WFrag<256, 4> f_h1;
    load_frag(f_h1, (t < 512) ? W_p1 : W_d1, t & 511);      // prefetch heads-1
    compute_frag<256, 320, 4>(f_fu, bias_lds + BFUSE, bufA, bufB, t);
    __syncthreads();

    // ---- L5: p1 (lower half-block) / d1 (upper half-block) ----
    WFrag<128, 8> f_h2;
    load_frag(f_h2, (t < 512) ? W_p2 : W_d2, t & 511);      // prefetch heads-2
    if (t < 512) compute_frag<128, 256, 4>(f_h1, bias_lds + BP1, bufB, bufA, t);
    else         compute_frag<128, 256, 4>(f_h1, bias_lds + BD1, bufB, bufA + 192, t - 512);
    __syncthreads();

    // ---- L6: p2 / d2 ----
    if (t < 512) compute_frag<64, 128, 8>(f_h2, bias_lds + BP2, bufA, bufB, t);
    else         compute_frag<64, 128, 8>(f_h2, bias_lds + BD2, bufA + 192, bufB + 64, t - 512);
    __syncthreads();

    // ---- final dots (weights preloaded): wave 0 -> price, wave 1 -> dir ----
    if (t < 64) {
        float v = wdot * bufB[t];
#pragma unroll
        for (int off = 32; off > 0; off >>= 1) v += __shfl_down(v, off, 64);
        if (t == 0) out[b] = v + bdot;
    } else if (t < 128) {
        const int u = t - 64;
        float v = wdot * bufB[64 + u];
#pragma unroll
        for (int off = 32; off > 0; off >>= 1) v += __shfl_down(v, off, 64);
        if (u == 0) {
            float z = v + bdot;
            out[B_ITEMS + b] = 1.0f / (1.0f + expf(-z));
        }
    }
}

extern "C" void kernel_launch(void* const* d_in, const int* in_sizes, int n_in,
                              void* d_out, int out_size, void* d_ws, size_t ws_size,
                              hipStream_t stream) {
    const float* x      = (const float*)d_in[0];
    const int*   cidx   = (const int*)  d_in[1];
    // d_in[2]=edge_index, d_in[3]=edge_attr -> numerically irrelevant
    const float* W_in   = (const float*)d_in[4];
    const float* b_in   = (const float*)d_in[5];
    const float* gat_W  = (const float*)d_in[6];
    // d_in[7..10] = att params -> irrelevant
    const float* gat_b  = (const float*)d_in[11];
    const float* emb    = (const float*)d_in[12];
    const float* W_fuse = (const float*)d_in[13];
    const float* b_fuse = (const float*)d_in[14];
    const float* W_p1   = (const float*)d_in[15];
    const float* b_p1   = (const float*)d_in[16];
    const float* W_p2   = (const float*)d_in[17];
    const float* b_p2   = (const float*)d_in[18];
    const float* W_p3   = (const float*)d_in[19];
    const float* b_p3   = (const float*)d_in[20];
    const float* W_d1   = (const float*)d_in[21];
    const float* b_d1   = (const float*)d_in[22];
    const float* W_d2   = (const float*)d_in[23];
    const float* b_d2   = (const float*)d_in[24];
    const float* W_d3   = (const float*)d_in[25];
    const float* b_d3   = (const float*)d_in[26];

    // d_ws unused: the fp16 compression is done in-register at load time
    // (workspace is re-poisoned every iteration, so a prepass could never be
    // hoisted anyway).
    (void)d_ws; (void)ws_size;

    fin_gat_v8<<<B_ITEMS, 1024, 0, stream>>>(
        x, cidx, W_in, b_in, gat_W, gat_b, emb, W_fuse, b_fuse,
        W_p1, b_p1, W_p2, b_p2, W_p3, b_p3,
        W_d1, b_d1, W_d2, b_d2, W_d3, b_d3,
        (float*)d_out);
}